// Round 5
// baseline (36.463 us; speedup 1.0000x reference)
//
#include <hip/hip_runtime.h>
#include <math.h>

#define EMBED 1280
#define NHEAD 20
#define HDIM 64
#define LENC 8192
#define CHUNK 128               // rows per block (4 independent waves x 32 rows)
#define NBLK (LENC / CHUNK)     // 64 blocks per head
#define NREC 256                // partial records per head (one per wave)
#define PREC 72                 // floats per record: [M,S,pad,pad,o[64]]
#define QSCALE 0.125f           // 64^-0.5

// ---------------------------------------------------------------------------
// q projection: one row per block, 256 threads, float4 loads.
// Block 0 also zeroes the `done` counter used by combine_outproj
// (kernel-boundary + LLC atomic store make it visible two launches later).
// ---------------------------------------------------------------------------
__global__ __launch_bounds__(256) void matvec_qproj(
    const float* __restrict__ W, const float* __restrict__ x,
    const float* __restrict__ b, float* __restrict__ y,
    int* __restrict__ done) {
  if (blockIdx.x == 0 && threadIdx.x == 0)
    __hip_atomic_store(done, 0, __ATOMIC_RELAXED, __HIP_MEMORY_SCOPE_AGENT);
  int row = blockIdx.x;
  int t = threadIdx.x;
  int w = t >> 6, lane = t & 63;
  const float4* Wr = reinterpret_cast<const float4*>(W + (size_t)row * EMBED);
  const float4* x4 = reinterpret_cast<const float4*>(x);
  float4 wv = Wr[t], xv = x4[t];
  float acc = wv.x * xv.x + wv.y * xv.y + wv.z * xv.z + wv.w * xv.w;
  if (t < 64) {
    float4 wv2 = Wr[256 + t], xv2 = x4[256 + t];
    acc += wv2.x * xv2.x + wv2.y * xv2.y + wv2.z * xv2.z + wv2.w * xv2.w;
  }
#pragma unroll
  for (int msk = 32; msk > 0; msk >>= 1) acc += __shfl_xor(acc, msk);
  __shared__ float red[4];
  if (lane == 0) red[w] = acc;
  __syncthreads();
  if (t == 0) y[row] = QSCALE * (red[0] + red[1] + red[2] + red[3] + b[row]);
}

// ---------------------------------------------------------------------------
// Flash-decode partial: each WAVE independently owns 32 keys.
// No LDS, no __syncthreads, no fences. 16 float4 loads in flight per lane.
// ---------------------------------------------------------------------------
__global__ __launch_bounds__(256) void attn_partial(
    const float* __restrict__ K, const float* __restrict__ V,
    const float* __restrict__ q, float* __restrict__ part) {
  int blk = blockIdx.x;   // 0..NHEAD*NBLK-1
  int h = blk / NBLK;
  int c = blk % NBLK;
  int tid = threadIdx.x;
  int w = tid >> 6;       // wave 0..3
  int lane = tid & 63;
  int grp = lane >> 4;    // row-group 0..3 within wave
  int l16 = lane & 15;    // float4 index within row

  size_t row0 = (size_t)c * CHUNK + (size_t)w * 32;
  const float4* Kh4 = reinterpret_cast<const float4*>(K + (size_t)h * LENC * HDIM) + row0 * 16;
  const float4* Vh4 = reinterpret_cast<const float4*>(V + (size_t)h * LENC * HDIM) + row0 * 16;
  float4 qv = reinterpret_cast<const float4*>(q + h * HDIM)[l16];

  float4 kreg[8], vreg[8];
#pragma unroll
  for (int it = 0; it < 8; ++it) kreg[it] = Kh4[(it * 4 + grp) * 16 + l16];
#pragma unroll
  for (int it = 0; it < 8; ++it) vreg[it] = Vh4[(it * 4 + grp) * 16 + l16];

  float s[8];
#pragma unroll
  for (int it = 0; it < 8; ++it) {
    float t = kreg[it].x * qv.x + kreg[it].y * qv.y + kreg[it].z * qv.z + kreg[it].w * qv.w;
    t += __shfl_xor(t, 1);
    t += __shfl_xor(t, 2);
    t += __shfl_xor(t, 4);
    t += __shfl_xor(t, 8);
    s[it] = t;
  }

  float m = s[0];
#pragma unroll
  for (int it = 1; it < 8; ++it) m = fmaxf(m, s[it]);
  m = fmaxf(m, __shfl_xor(m, 16));
  m = fmaxf(m, __shfl_xor(m, 32));

  float e[8], ssum = 0.f;
#pragma unroll
  for (int it = 0; it < 8; ++it) { e[it] = expf(s[it] - m); ssum += e[it]; }
  ssum += __shfl_xor(ssum, 16);
  ssum += __shfl_xor(ssum, 32);

  float4 o = make_float4(0.f, 0.f, 0.f, 0.f);
#pragma unroll
  for (int it = 0; it < 8; ++it) {
    o.x += e[it] * vreg[it].x;
    o.y += e[it] * vreg[it].y;
    o.z += e[it] * vreg[it].z;
    o.w += e[it] * vreg[it].w;
  }
#pragma unroll
  for (int msk = 16; msk <= 32; msk <<= 1) {
    o.x += __shfl_xor(o.x, msk);
    o.y += __shfl_xor(o.y, msk);
    o.z += __shfl_xor(o.z, msk);
    o.w += __shfl_xor(o.w, msk);
  }

  float* p = part + (size_t)(h * NREC + c * 4 + w) * PREC;
  if (grp == 0) {
    if (l16 == 0) { p[0] = m; p[1] = ssum; }
    reinterpret_cast<float4*>(p + 4)[l16] = o;
  }
}

// ---------------------------------------------------------------------------
// Fused combine + output projection. 1280 blocks, one output row each.
// Blocks 0..19 first combine head=blockIdx (publish attn_out via LLC-direct
// relaxed atomic stores + ONE release each). All blocks preload their weight
// row, poll the counter with relaxed atomic loads (no acquire fences), read
// attn_out via relaxed atomics, then finish the matvec.
// ---------------------------------------------------------------------------
__global__ __launch_bounds__(256) void combine_outproj(
    const float* __restrict__ part, const float* __restrict__ W,
    const float* __restrict__ b, float* __restrict__ attn_out,
    int* __restrict__ done, float* __restrict__ out) {
  int row = blockIdx.x;
  int t = threadIdx.x;
  int w = t >> 6, lane = t & 63;

  // preload weight row (hides the poll wait)
  const float4* Wr = reinterpret_cast<const float4*>(W + (size_t)row * EMBED);
  float4 wv = Wr[t];
  float4 wv2 = make_float4(0.f, 0.f, 0.f, 0.f);
  if (t < 64) wv2 = Wr[256 + t];

  __shared__ float red[4];

  // ---- producer phase: combine one head ----
  if (row < NHEAD) {
    __shared__ float fsh[NREC];
    __shared__ float redM[4], redS[4];
    __shared__ float osum[4][HDIM];
    const float* p = part + (size_t)row * NREC * PREC;
    float mt = p[t * PREC];
    float st = p[t * PREC + 1];
    float m = mt;
#pragma unroll
    for (int msk = 32; msk > 0; msk >>= 1) m = fmaxf(m, __shfl_xor(m, msk));
    if (lane == 0) redM[w] = m;
    __syncthreads();
    float Mg = fmaxf(fmaxf(redM[0], redM[1]), fmaxf(redM[2], redM[3]));
    float f = expf(mt - Mg);
    fsh[t] = f;
    float sc = st * f;
#pragma unroll
    for (int msk = 32; msk > 0; msk >>= 1) sc += __shfl_xor(sc, msk);
    if (lane == 0) redS[w] = sc;
    __syncthreads();
    float Sg = redS[0] + redS[1] + redS[2] + redS[3];

    float o = 0.f;
#pragma unroll 4
    for (int r = 0; r < 64; ++r) {
      int rec = w * 64 + r;
      o += fsh[rec] * p[rec * PREC + 4 + lane];
    }
    osum[w][lane] = o;
    __syncthreads();
    if (w == 0) {
      float oo = (osum[0][lane] + osum[1][lane] + osum[2][lane] + osum[3][lane]) / Sg;
      __hip_atomic_store(&attn_out[row * HDIM + lane], oo, __ATOMIC_RELAXED,
                         __HIP_MEMORY_SCOPE_AGENT);
    }
    __syncthreads();
    if (t == 0)
      __hip_atomic_fetch_add(done, 1, __ATOMIC_RELEASE, __HIP_MEMORY_SCOPE_AGENT);
  }

  // ---- consumer phase: wait for all 20 heads ----
  if (t == 0) {
    while (__hip_atomic_load(done, __ATOMIC_RELAXED, __HIP_MEMORY_SCOPE_AGENT) < NHEAD)
      __builtin_amdgcn_s_sleep(2);
  }
  __syncthreads();

  // x chunk t = attn_out[4t..4t+3], via LLC-direct relaxed atomic loads
  float acc;
  {
    float x0 = __hip_atomic_load(&attn_out[4 * t + 0], __ATOMIC_RELAXED, __HIP_MEMORY_SCOPE_AGENT);
    float x1 = __hip_atomic_load(&attn_out[4 * t + 1], __ATOMIC_RELAXED, __HIP_MEMORY_SCOPE_AGENT);
    float x2 = __hip_atomic_load(&attn_out[4 * t + 2], __ATOMIC_RELAXED, __HIP_MEMORY_SCOPE_AGENT);
    float x3 = __hip_atomic_load(&attn_out[4 * t + 3], __ATOMIC_RELAXED, __HIP_MEMORY_SCOPE_AGENT);
    acc = wv.x * x0 + wv.y * x1 + wv.z * x2 + wv.w * x3;
  }
  if (t < 64) {
    int base = 1024 + 4 * t;
    float x0 = __hip_atomic_load(&attn_out[base + 0], __ATOMIC_RELAXED, __HIP_MEMORY_SCOPE_AGENT);
    float x1 = __hip_atomic_load(&attn_out[base + 1], __ATOMIC_RELAXED, __HIP_MEMORY_SCOPE_AGENT);
    float x2 = __hip_atomic_load(&attn_out[base + 2], __ATOMIC_RELAXED, __HIP_MEMORY_SCOPE_AGENT);
    float x3 = __hip_atomic_load(&attn_out[base + 3], __ATOMIC_RELAXED, __HIP_MEMORY_SCOPE_AGENT);
    acc += wv2.x * x0 + wv2.y * x1 + wv2.z * x2 + wv2.w * x3;
  }
#pragma unroll
  for (int msk = 32; msk > 0; msk >>= 1) acc += __shfl_xor(acc, msk);
  if (lane == 0) red[w] = acc;
  __syncthreads();
  if (t == 0) out[row] = red[0] + red[1] + red[2] + red[3] + b[row];
}

// ---------------------------------------------------------------------------

extern "C" void kernel_launch(void* const* d_in, const int* in_sizes, int n_in,
                              void* d_out, int out_size, void* d_ws, size_t ws_size,
                              hipStream_t stream) {
  const float* hs    = (const float*)d_in[0];  // [1280]
  const float* Kc    = (const float*)d_in[1];  // [20,8192,64]
  const float* Vc    = (const float*)d_in[2];  // [20,8192,64]
  const float* q_w   = (const float*)d_in[3];  // [1280,1280]
  const float* q_b   = (const float*)d_in[4];  // [1280]
  const float* out_w = (const float*)d_in[5];  // [1280,1280]
  const float* out_b = (const float*)d_in[6];  // [1280]
  float* out = (float*)d_out;                  // [1280]

  float* ws = (float*)d_ws;
  int*   done     = (int*)ws;           // combine arrival counter
  float* qv       = ws + 32;            // 1280
  float* attn_out = ws + 32 + EMBED;    // 1280
  float* part     = ws + 32 + 2 * EMBED;  // 20*256*72 floats (16B-aligned)

  // 1. q projection (+ scale), zeroes `done`
  matvec_qproj<<<EMBED, 256, 0, stream>>>(q_w, hs, q_b, qv, done);
  // 2. flash-decode partials (wave-independent, no barriers)
  attn_partial<<<NHEAD * NBLK, 256, 0, stream>>>(Kc, Vc, qv, part);
  // 3. fused combine + output projection
  combine_outproj<<<EMBED, 256, 0, stream>>>(part, out_w, out_b, attn_out, done, out);
}

// Round 6
// 30.694 us; speedup vs baseline: 1.1879x; 1.1879x over previous
//
#include <hip/hip_runtime.h>
#include <math.h>

#define EMBED 1280
#define NHEAD 20
#define HDIM 64
#define LENC 8192
#define WROWS 64                // rows per wave (deep pipeline: 32 float4 in flight)
#define BROWS 128               // rows per block (2 waves x 64 rows)
#define NBLK (LENC / BROWS)     // 64 blocks per head
#define NREC 128                // partial records per head (one per wave)
#define PREC 72                 // floats per record: [M,S,pad,pad,o[64]]
#define QSCALE 0.125f           // 64^-0.5

// ---------------------------------------------------------------------------
// matvec: one row per block, 256 threads, float4 loads.
// y[row] = scale * (W[row,:] . x + b[row])
// ---------------------------------------------------------------------------
__global__ __launch_bounds__(256) void matvec_row(
    const float* __restrict__ W, const float* __restrict__ x,
    const float* __restrict__ b, float* __restrict__ y, float scale) {
  int row = blockIdx.x;
  int t = threadIdx.x;
  int w = t >> 6, lane = t & 63;
  const float4* Wr = reinterpret_cast<const float4*>(W + (size_t)row * EMBED);
  const float4* x4 = reinterpret_cast<const float4*>(x);
  float4 wv = Wr[t], xv = x4[t];
  float acc = wv.x * xv.x + wv.y * xv.y + wv.z * xv.z + wv.w * xv.w;
  if (t < 64) {
    float4 wv2 = Wr[256 + t], xv2 = x4[256 + t];
    acc += wv2.x * xv2.x + wv2.y * xv2.y + wv2.z * xv2.z + wv2.w * xv2.w;
  }
#pragma unroll
  for (int msk = 32; msk > 0; msk >>= 1) acc += __shfl_xor(acc, msk);
  __shared__ float red[4];
  if (lane == 0) red[w] = acc;
  __syncthreads();
  if (t == 0) y[row] = scale * (red[0] + red[1] + red[2] + red[3] + b[row]);
}

// ---------------------------------------------------------------------------
// Flash-decode partial: each WAVE independently owns 64 keys.
// All 16 K + 16 V float4 loads issued up front (512B/lane in flight).
// No LDS, no __syncthreads, no fences. 16 lanes span one 64-float row;
// quarter-wave grp handles rows it*4+grp, it = 0..15.
// Record per wave: [M, S, pad, pad, o[64]] (o unnormalized).
// ---------------------------------------------------------------------------
__global__ __launch_bounds__(128) void attn_partial(
    const float* __restrict__ K, const float* __restrict__ V,
    const float* __restrict__ q, float* __restrict__ part) {
  int blk = blockIdx.x;   // 0..NHEAD*NBLK-1
  int h = blk / NBLK;
  int c = blk % NBLK;
  int tid = threadIdx.x;
  int w = tid >> 6;       // wave 0..1
  int lane = tid & 63;
  int grp = lane >> 4;    // row-group 0..3 within wave
  int l16 = lane & 15;    // float4 index within row

  size_t row0 = (size_t)c * BROWS + (size_t)w * WROWS;
  const float4* Kh4 = reinterpret_cast<const float4*>(K + (size_t)h * LENC * HDIM) + row0 * 16;
  const float4* Vh4 = reinterpret_cast<const float4*>(V + (size_t)h * LENC * HDIM) + row0 * 16;
  float4 qv = reinterpret_cast<const float4*>(q + h * HDIM)[l16];

  // issue ALL loads up front: 16 K + 16 V per lane (vmcnt in-order completion
  // lets score compute start as soon as the first K returns)
  float4 kreg[16], vreg[16];
#pragma unroll
  for (int it = 0; it < 16; ++it) kreg[it] = Kh4[(it * 4 + grp) * 16 + l16];
#pragma unroll
  for (int it = 0; it < 16; ++it) vreg[it] = Vh4[(it * 4 + grp) * 16 + l16];

  // scores for my group's 16 rows (replicated across the 16 lanes of the group)
  float s[16];
#pragma unroll
  for (int it = 0; it < 16; ++it) {
    float t = kreg[it].x * qv.x + kreg[it].y * qv.y + kreg[it].z * qv.z + kreg[it].w * qv.w;
    t += __shfl_xor(t, 1);
    t += __shfl_xor(t, 2);
    t += __shfl_xor(t, 4);
    t += __shfl_xor(t, 8);
    s[it] = t;
  }

  // wave-local softmax over 64 rows (reduce across the 4 groups: xor 16, 32)
  float m = s[0];
#pragma unroll
  for (int it = 1; it < 16; ++it) m = fmaxf(m, s[it]);
  m = fmaxf(m, __shfl_xor(m, 16));
  m = fmaxf(m, __shfl_xor(m, 32));

  float e[16], ssum = 0.f;
#pragma unroll
  for (int it = 0; it < 16; ++it) { e[it] = expf(s[it] - m); ssum += e[it]; }
  ssum += __shfl_xor(ssum, 16);
  ssum += __shfl_xor(ssum, 32);

  // P @ V for my group's rows, dims [l16*4, l16*4+4)
  float4 o = make_float4(0.f, 0.f, 0.f, 0.f);
#pragma unroll
  for (int it = 0; it < 16; ++it) {
    o.x += e[it] * vreg[it].x;
    o.y += e[it] * vreg[it].y;
    o.z += e[it] * vreg[it].z;
    o.w += e[it] * vreg[it].w;
  }
#pragma unroll
  for (int msk = 16; msk <= 32; msk <<= 1) {
    o.x += __shfl_xor(o.x, msk);
    o.y += __shfl_xor(o.y, msk);
    o.z += __shfl_xor(o.z, msk);
    o.w += __shfl_xor(o.w, msk);
  }

  float* p = part + (size_t)(h * NREC + c * 2 + w) * PREC;
  if (grp == 0) {
    if (l16 == 0) { p[0] = m; p[1] = ssum; }
    reinterpret_cast<float4*>(p + 4)[l16] = o;
  }
}

// ---------------------------------------------------------------------------
// Combine 128 partials per head: 20 blocks x 256 threads.
// Threads 0..127 own record t's (M,S); wave w accumulates o over records
// [32w, 32w+32) (coalesced 256B record reads).
// ---------------------------------------------------------------------------
__global__ __launch_bounds__(256) void attn_combine(
    const float* __restrict__ part, float* __restrict__ attn_out) {
  int h = blockIdx.x;
  int tid = threadIdx.x;
  int w = tid >> 6, lane = tid & 63;
  const float* p = part + (size_t)h * NREC * PREC;

  __shared__ float fsh[NREC];
  __shared__ float redM[4], redS[4];
  __shared__ float osum[4][HDIM];

  float mt = (tid < NREC) ? p[tid * PREC] : -INFINITY;
  float st = (tid < NREC) ? p[tid * PREC + 1] : 0.f;
  float m = mt;
#pragma unroll
  for (int msk = 32; msk > 0; msk >>= 1) m = fmaxf(m, __shfl_xor(m, msk));
  if (lane == 0) redM[w] = m;
  __syncthreads();
  float Mg = fmaxf(fmaxf(redM[0], redM[1]), fmaxf(redM[2], redM[3]));

  float f = (tid < NREC) ? expf(mt - Mg) : 0.f;
  if (tid < NREC) fsh[tid] = f;
  float sc = st * f;
#pragma unroll
  for (int msk = 32; msk > 0; msk >>= 1) sc += __shfl_xor(sc, msk);
  if (lane == 0) redS[w] = sc;
  __syncthreads();
  float Sg = redS[0] + redS[1] + redS[2] + redS[3];

  // o[lane] accumulated over this wave's 32 records (coalesced 256B reads)
  float o = 0.f;
#pragma unroll 4
  for (int r = 0; r < NREC / 4; ++r) {
    int rec = w * (NREC / 4) + r;
    o += fsh[rec] * p[rec * PREC + 4 + lane];
  }
  osum[w][lane] = o;
  __syncthreads();
  if (w == 0) {
    float oo = osum[0][lane] + osum[1][lane] + osum[2][lane] + osum[3][lane];
    attn_out[h * HDIM + lane] = oo / Sg;
  }
}

// ---------------------------------------------------------------------------

extern "C" void kernel_launch(void* const* d_in, const int* in_sizes, int n_in,
                              void* d_out, int out_size, void* d_ws, size_t ws_size,
                              hipStream_t stream) {
  const float* hs    = (const float*)d_in[0];  // [1280]
  const float* Kc    = (const float*)d_in[1];  // [20,8192,64]
  const float* Vc    = (const float*)d_in[2];  // [20,8192,64]
  const float* q_w   = (const float*)d_in[3];  // [1280,1280]
  const float* q_b   = (const float*)d_in[4];  // [1280]
  const float* out_w = (const float*)d_in[5];  // [1280,1280]
  const float* out_b = (const float*)d_in[6];  // [1280]
  float* out = (float*)d_out;                  // [1280]

  float* ws = (float*)d_ws;
  float* qv       = ws;                 // 1280
  float* attn_out = ws + EMBED;         // 1280
  float* part     = ws + 2 * EMBED;     // 20*128*72 floats (16B-aligned)

  // 1. q projection (+ scale)
  matvec_row<<<EMBED, 256, 0, stream>>>(q_w, hs, q_b, qv, QSCALE);
  // 2. flash-decode partials (wave-independent, 64 rows/wave deep pipeline)
  attn_partial<<<NHEAD * NBLK, 128, 0, stream>>>(Kc, Vc, qv, part);
  // 3. combine 128 records per head
  attn_combine<<<NHEAD, 256, 0, stream>>>(part, attn_out);
  // 4. output projection
  matvec_row<<<EMBED, 256, 0, stream>>>(out_w, attn_out, out_b, out, 1.0f);
}